// Round 1
// baseline (1599.010 us; speedup 1.0000x reference)
//
#include <hip/hip_runtime.h>

typedef unsigned short u16;
typedef unsigned int u32;
typedef unsigned long long u64;

#define T_TOK 8192
#define DIM 768
#define FF 3072
#define NE 8
#define CAP 2560
#define LSTR 5120
#define MAXMT 40

typedef __attribute__((ext_vector_type(8))) short s8v;
typedef __attribute__((ext_vector_type(4))) float f4v;

__device__ __forceinline__ u16 f2bf(float f) {
  union { float f; u32 u; } v; v.f = f;
  u32 r = v.u + 0x7FFFu + ((v.u >> 16) & 1u);
  return (u16)(r >> 16);
}

__device__ __forceinline__ void glds16(const void* g, void* l) {
  __builtin_amdgcn_global_load_lds(
      (const __attribute__((address_space(1))) u32*)g,
      (__attribute__((address_space(3))) u32*)l, 16, 0, 0);
}

// ---------------- cast fp32 -> bf16, 8 elems/thread ----------------
__global__ void cast_bf16_kernel(const float* __restrict__ src, u16* __restrict__ dst, int n8) {
  int i = blockIdx.x * blockDim.x + threadIdx.x;
  if (i >= n8) return;
  const float4* s4 = (const float4*)src;
  float4 a = s4[2 * i], b = s4[2 * i + 1];
  uint4 o;
  o.x = (u32)f2bf(a.x) | ((u32)f2bf(a.y) << 16);
  o.y = (u32)f2bf(a.z) | ((u32)f2bf(a.w) << 16);
  o.z = (u32)f2bf(b.x) | ((u32)f2bf(b.y) << 16);
  o.w = (u32)f2bf(b.z) | ((u32)f2bf(b.w) << 16);
  ((uint4*)dst)[i] = o;
}

// ---------------- router: one wave per token ----------------
__global__ __launch_bounds__(256) void router_kernel(
    const float* __restrict__ x, const float* __restrict__ wg,
    int* __restrict__ tki, float* __restrict__ tkp,
    int* __restrict__ fcnt, float* __restrict__ psum, float* __restrict__ zsum) {
  int lane = threadIdx.x & 63;
  int t = blockIdx.x * 4 + (threadIdx.x >> 6);
  const float* xr = x + (long)t * DIM;
  float acc[NE];
#pragma unroll
  for (int e = 0; e < NE; e++) acc[e] = 0.f;
  for (int i = 0; i < DIM / 64; i++) {
    float xv = xr[lane + 64 * i];
#pragma unroll
    for (int e = 0; e < NE; e++) acc[e] += xv * wg[e * DIM + lane + 64 * i];
  }
#pragma unroll
  for (int off = 32; off > 0; off >>= 1) {
#pragma unroll
    for (int e = 0; e < NE; e++) acc[e] += __shfl_xor(acc[e], off);
  }
  if (lane == 0) {
    float m = acc[0];
#pragma unroll
    for (int e = 1; e < NE; e++) m = fmaxf(m, acc[e]);
    float p[NE], s = 0.f;
#pragma unroll
    for (int e = 0; e < NE; e++) { p[e] = expf(acc[e] - m); s += p[e]; }
    float inv = 1.f / s;
    int e0 = 0;
#pragma unroll
    for (int e = 1; e < NE; e++) if (acc[e] > acc[e0]) e0 = e;
    int e1 = (e0 == 0) ? 1 : 0;
#pragma unroll
    for (int e = 0; e < NE; e++) if (e != e0 && acc[e] > acc[e1]) e1 = e;
    float p0 = p[e0] * inv, p1 = p[e1] * inv;
    float rn = 1.f / (p0 + p1);
    tki[2 * t] = e0; tki[2 * t + 1] = e1;
    tkp[2 * t] = p0 * rn; tkp[2 * t + 1] = p1 * rn;
    atomicAdd(&fcnt[e0], 1); atomicAdd(&fcnt[e1], 1);
    float lse = logf(s) + m;
    atomicAdd(zsum, lse * lse);
#pragma unroll
    for (int e = 0; e < NE; e++) atomicAdd(&psum[e], p[e] * inv);
  }
}

// ---------------- rank + dispatch (exact capacity semantics) ----------------
__global__ __launch_bounds__(1024) void rank_dispatch_kernel(
    const int* __restrict__ tki, const float* __restrict__ tkp,
    int* __restrict__ ltk, float* __restrict__ lw, int* __restrict__ keep,
    int* __restrict__ counts, int* __restrict__ baserow) {
  __shared__ int wave_cnt[2][16][8];
  __shared__ int base[2][8];
  __shared__ int epos[8];
  int tid = threadIdx.x, wv = tid >> 6, lane = tid & 63;
  if (tid < 16) base[tid >> 3][tid & 7] = 0;
  if (tid < 8) epos[tid] = 0;
  __syncthreads();
  u64 lmask = (lane == 63) ? 0x7FFFFFFFFFFFFFFFull : ((1ull << lane) - 1ull);
  for (int c = 0; c < T_TOK / 1024; c++) {
    int t = c * 1024 + tid;
    int e0 = tki[2 * t], e1 = tki[2 * t + 1];
    float p0 = tkp[2 * t], p1 = tkp[2 * t + 1];
    int pre0 = 0, pre1 = 0;
    for (int e = 0; e < 8; e++) {
      u64 m0 = __ballot(e0 == e);
      if (e0 == e) pre0 = __popcll(m0 & lmask);
      if (lane == 0) wave_cnt[0][wv][e] = __popcll(m0);
      u64 m1 = __ballot(e1 == e);
      if (e1 == e) pre1 = __popcll(m1 & lmask);
      if (lane == 0) wave_cnt[1][wv][e] = __popcll(m1);
    }
    __syncthreads();
    if (tid < 16) {
      int k = tid >> 3, e = tid & 7;
      int run = base[k][e];
      for (int w = 0; w < 16; w++) {
        int v = wave_cnt[k][w][e];
        wave_cnt[k][w][e] = run;
        run += v;
      }
      base[k][e] = run;
    }
    __syncthreads();
    int r0 = wave_cnt[0][wv][e0] + pre0;
    int r1 = wave_cnt[1][wv][e1] + pre1;
    int k0 = (r0 < CAP) ? 1 : 0;
    int k1 = (r1 < CAP) ? 1 : 0;
    keep[t] = k0 | (k1 << 1);
    if (k0) { int p = atomicAdd(&epos[e0], 1); ltk[e0 * LSTR + p] = (t << 1); lw[e0 * LSTR + p] = p0; }
    if (k1) { int p = atomicAdd(&epos[e1], 1); ltk[e1 * LSTR + p] = (t << 1) | 1; lw[e1 * LSTR + p] = p1; }
    __syncthreads();
  }
  if (tid == 0) {
    int run = 0;
    for (int e = 0; e < 8; e++) { counts[e] = epos[e]; baserow[e] = run; run += epos[e]; }
  }
}

// ---------------- GEMM1: H = silu(x@Wg^T) * (x@Wu^T), gathered rows ----------------
__global__ __launch_bounds__(256, 2) void gemm1_kernel(
    const u16* __restrict__ xb, const u16* __restrict__ wgb, const u16* __restrict__ wub,
    u16* __restrict__ H, const int* __restrict__ counts, const int* __restrict__ baserow,
    const int* __restrict__ ltk) {
  int e = blockIdx.x / MAXMT, mt = blockIdx.x % MAXMT;
  int cnt = counts[e];
  if (mt * 128 >= cnt) return;
  int nt = blockIdx.y;
  __shared__ u16 As[128 * 32];
  __shared__ u16 Bg[128 * 32];
  __shared__ u16 Bu[128 * 32];
  __shared__ int toks[128];
  int tid = threadIdx.x;
  if (tid < 128) {
    int r = mt * 128 + tid; if (r > cnt - 1) r = cnt - 1;
    toks[tid] = ltk[e * LSTR + r] >> 1;
  }
  __syncthreads();
  int rq = tid >> 2;
  int kc = (tid & 3) * 8;
  long tA0 = toks[rq], tA1 = toks[64 + rq];
  const u16* gA0 = xb + tA0 * DIM + kc;
  const u16* gA1 = xb + tA1 * DIM + kc;
  long bOff = ((long)e * FF + nt * 128 + rq) * DIM + kc;
  const u16* gG0 = wgb + bOff;
  const u16* gG1 = wgb + bOff + 64l * DIM;
  const u16* gU0 = wub + bOff;
  const u16* gU1 = wub + bOff + 64l * DIM;
  u16* dA0 = As + tid * 8; u16* dA1 = As + (256 + tid) * 8;
  u16* dG0 = Bg + tid * 8; u16* dG1 = Bg + (256 + tid) * 8;
  u16* dU0 = Bu + tid * 8; u16* dU1 = Bu + (256 + tid) * 8;

  int lane = tid & 63, wv = tid >> 6;
  int wm = (wv & 1) * 64, wn = (wv >> 1) * 64;
  int lrow = lane & 15, quad = lane >> 4;

  f4v zero = {0.f, 0.f, 0.f, 0.f};
  f4v accg[4][4], accu[4][4];
#pragma unroll
  for (int i = 0; i < 4; i++)
#pragma unroll
    for (int j = 0; j < 4; j++) { accg[i][j] = zero; accu[i][j] = zero; }

  for (int kt = 0; kt < DIM / 32; kt++) {
    int ko = kt * 32;
    __syncthreads();
    glds16(gA0 + ko, dA0); glds16(gA1 + ko, dA1);
    glds16(gG0 + ko, dG0); glds16(gG1 + ko, dG1);
    glds16(gU0 + ko, dU0); glds16(gU1 + ko, dU1);
    __syncthreads();
    s8v a[4], bg[4], bu[4];
#pragma unroll
    for (int i = 0; i < 4; i++)
      a[i] = *(const s8v*)&As[(wm + i * 16 + lrow) * 32 + quad * 8];
#pragma unroll
    for (int j = 0; j < 4; j++) {
      bg[j] = *(const s8v*)&Bg[(wn + j * 16 + lrow) * 32 + quad * 8];
      bu[j] = *(const s8v*)&Bu[(wn + j * 16 + lrow) * 32 + quad * 8];
    }
#pragma unroll
    for (int i = 0; i < 4; i++)
#pragma unroll
      for (int j = 0; j < 4; j++) {
        accg[i][j] = __builtin_amdgcn_mfma_f32_16x16x32_bf16(a[i], bg[j], accg[i][j], 0, 0, 0);
        accu[i][j] = __builtin_amdgcn_mfma_f32_16x16x32_bf16(a[i], bu[j], accu[i][j], 0, 0, 0);
      }
  }
  long hb = (long)baserow[e] + (long)mt * 128;
#pragma unroll
  for (int i = 0; i < 4; i++) {
#pragma unroll
    for (int r = 0; r < 4; r++) {
      int m = wm + i * 16 + quad * 4 + r;
      if (mt * 128 + m < cnt) {
#pragma unroll
        for (int j = 0; j < 4; j++) {
          float g = accg[i][j][r], u = accu[i][j][r];
          float h = g / (1.f + __expf(-g)) * u;
          H[(hb + m) * FF + nt * 128 + wn + j * 16 + lrow] = f2bf(h);
        }
      }
    }
  }
}

// ---------------- GEMM2: y = H @ wo^T, scaled by combine weight ----------------
__global__ __launch_bounds__(256, 2) void gemm2_kernel(
    const u16* __restrict__ H, const u16* __restrict__ wob,
    float* __restrict__ ybuf, const int* __restrict__ counts, const int* __restrict__ baserow,
    const int* __restrict__ ltk, const float* __restrict__ lw) {
  int e = blockIdx.x / MAXMT, mt = blockIdx.x % MAXMT;
  int cnt = counts[e];
  if (mt * 128 >= cnt) return;
  int nt = blockIdx.y;
  __shared__ u16 As[128 * 32];
  __shared__ u16 Bs[128 * 32];
  __shared__ int stok[128];
  __shared__ float sw[128];
  int tid = threadIdx.x;
  if (tid < 128) {
    int r = mt * 128 + tid; if (r > cnt - 1) r = cnt - 1;
    stok[tid] = ltk[e * LSTR + r];
    sw[tid] = lw[e * LSTR + r];
  }
  long hb = (long)baserow[e] + (long)mt * 128;
  int rq = tid >> 2, kc = (tid & 3) * 8;
  const u16* gA0 = H + (hb + rq) * FF + kc;
  const u16* gA1 = gA0 + 64l * FF;
  long bOff = ((long)e * DIM + nt * 128 + rq) * FF + kc;
  const u16* gB0 = wob + bOff;
  const u16* gB1 = gB0 + 64l * FF;
  u16* dA0 = As + tid * 8; u16* dA1 = As + (256 + tid) * 8;
  u16* dB0 = Bs + tid * 8; u16* dB1 = Bs + (256 + tid) * 8;
  int lane = tid & 63, wv = tid >> 6;
  int wm = (wv & 1) * 64, wn = (wv >> 1) * 64;
  int lrow = lane & 15, quad = lane >> 4;
  f4v zero = {0.f, 0.f, 0.f, 0.f};
  f4v acc[4][4];
#pragma unroll
  for (int i = 0; i < 4; i++)
#pragma unroll
    for (int j = 0; j < 4; j++) acc[i][j] = zero;

  for (int kt = 0; kt < FF / 32; kt++) {
    int ko = kt * 32;
    __syncthreads();
    glds16(gA0 + ko, dA0); glds16(gA1 + ko, dA1);
    glds16(gB0 + ko, dB0); glds16(gB1 + ko, dB1);
    __syncthreads();
    s8v a[4], b[4];
#pragma unroll
    for (int i = 0; i < 4; i++)
      a[i] = *(const s8v*)&As[(wm + i * 16 + lrow) * 32 + quad * 8];
#pragma unroll
    for (int j = 0; j < 4; j++)
      b[j] = *(const s8v*)&Bs[(wn + j * 16 + lrow) * 32 + quad * 8];
#pragma unroll
    for (int i = 0; i < 4; i++)
#pragma unroll
      for (int j = 0; j < 4; j++)
        acc[i][j] = __builtin_amdgcn_mfma_f32_16x16x32_bf16(a[i], b[j], acc[i][j], 0, 0, 0);
  }
#pragma unroll
  for (int i = 0; i < 4; i++) {
#pragma unroll
    for (int r = 0; r < 4; r++) {
      int m = wm + i * 16 + quad * 4 + r;
      if (mt * 128 + m < cnt) {
        int entry = stok[m];
        int t = entry >> 1, k = entry & 1;
        float w = sw[m];
        long ob = ((long)(k * T_TOK + t)) * DIM + nt * 128;
#pragma unroll
        for (int j = 0; j < 4; j++)
          ybuf[ob + wn + j * 16 + lrow] = acc[i][j][r] * w;
      }
    }
  }
}

// ---------------- combine two slots -> out ----------------
__global__ void combine_kernel(const float* __restrict__ ybuf, const int* __restrict__ keep,
                               float* __restrict__ out) {
  int idx = blockIdx.x * 256 + threadIdx.x;
  int t = idx / (DIM / 4);
  int km = keep[t];
  const float4* y4 = (const float4*)ybuf;
  float4 r = {0.f, 0.f, 0.f, 0.f};
  if (km & 1) r = y4[idx];
  if (km & 2) {
    float4 b = y4[T_TOK * (DIM / 4) + idx];
    r.x += b.x; r.y += b.y; r.z += b.z; r.w += b.w;
  }
  ((float4*)out)[idx] = r;
}

// ---------------- aux loss ----------------
__global__ void aux_kernel(const int* __restrict__ fcnt, const float* __restrict__ psum,
                           const float* __restrict__ zsum, float* __restrict__ outaux) {
  if (threadIdx.x == 0 && blockIdx.x == 0) {
    float lb = 0.f;
    for (int e = 0; e < 8; e++)
      lb += ((float)fcnt[e] / (float)(T_TOK * 2)) * (psum[e] / (float)T_TOK);
    lb *= 8.f;
    float z = zsum[0] / (float)T_TOK;
    outaux[0] = 0.01f * lb + 0.001f * z;
  }
}

extern "C" void kernel_launch(void* const* d_in, const int* in_sizes, int n_in,
                              void* d_out, int out_size, void* d_ws, size_t ws_size,
                              hipStream_t stream) {
  const float* x = (const float*)d_in[0];
  const float* wgate = (const float*)d_in[1];
  const float* wig = (const float*)d_in[2];
  const float* wiu = (const float*)d_in[3];
  const float* wo = (const float*)d_in[4];
  float* out = (float*)d_out;

  char* ws = (char*)d_ws;
  size_t off = 0;
  auto alloc = [&](size_t bytes) {
    void* p = ws + off;
    off += (bytes + 255) & ~(size_t)255;
    return p;
  };
  int* ctrl = (int*)alloc(256);
  u16* xb = (u16*)alloc((size_t)T_TOK * DIM * 2);
  u16* wgb = (u16*)alloc((size_t)NE * FF * DIM * 2);
  u16* wub = (u16*)alloc((size_t)NE * FF * DIM * 2);
  u16* wob = (u16*)alloc((size_t)NE * DIM * FF * 2);
  u16* Hbuf = (u16*)alloc((size_t)(T_TOK * 2 + 128) * FF * 2);
  float* ybuf = (float*)alloc((size_t)2 * T_TOK * DIM * 4);
  int* tki = (int*)alloc((size_t)T_TOK * 2 * 4);
  float* tkp = (float*)alloc((size_t)T_TOK * 2 * 4);
  int* ltk = (int*)alloc((size_t)NE * LSTR * 4);
  float* lw = (float*)alloc((size_t)NE * LSTR * 4);
  int* keep = (int*)alloc((size_t)T_TOK * 4);

  int* fcnt = ctrl;
  int* counts = ctrl + 8;
  int* baserow = ctrl + 16;
  float* psum = (float*)(ctrl + 24);
  float* zsum = (float*)(ctrl + 32);

  hipMemsetAsync(ctrl, 0, 256, stream);
  cast_bf16_kernel<<<T_TOK * DIM / 8 / 256, 256, 0, stream>>>(x, xb, T_TOK * DIM / 8);
  cast_bf16_kernel<<<NE * FF * DIM / 8 / 256, 256, 0, stream>>>(wig, wgb, NE * FF * DIM / 8);
  cast_bf16_kernel<<<NE * FF * DIM / 8 / 256, 256, 0, stream>>>(wiu, wub, NE * FF * DIM / 8);
  cast_bf16_kernel<<<NE * DIM * FF / 8 / 256, 256, 0, stream>>>(wo, wob, NE * DIM * FF / 8);
  router_kernel<<<T_TOK / 4, 256, 0, stream>>>(x, wgate, tki, tkp, fcnt, psum, zsum);
  rank_dispatch_kernel<<<1, 1024, 0, stream>>>(tki, tkp, ltk, lw, keep, counts, baserow);
  gemm1_kernel<<<dim3(NE * MAXMT, FF / 128), 256, 0, stream>>>(xb, wgb, wub, Hbuf, counts, baserow, ltk);
  gemm2_kernel<<<dim3(NE * MAXMT, DIM / 128), 256, 0, stream>>>(Hbuf, wob, ybuf, counts, baserow, ltk, lw);
  combine_kernel<<<T_TOK * DIM / 4 / 256, 256, 0, stream>>>(ybuf, keep, out);
  aux_kernel<<<1, 64, 0, stream>>>(fcnt, psum, zsum, out + (size_t)T_TOK * DIM);
}

// Round 2
// 751.874 us; speedup vs baseline: 2.1267x; 2.1267x over previous
//
#include <hip/hip_runtime.h>

typedef unsigned short u16;
typedef unsigned int u32;
typedef unsigned long long u64;

#define T_TOK 8192
#define DIM 768
#define FF 3072
#define NE 8
#define CAP 2560
#define LSTR 5120
#define MAXMT 40

typedef __attribute__((ext_vector_type(8))) short s8v;
typedef __attribute__((ext_vector_type(4))) float f4v;

__device__ __forceinline__ u16 f2bf(float f) {
  union { float f; u32 u; } v; v.f = f;
  u32 r = v.u + 0x7FFFu + ((v.u >> 16) & 1u);
  return (u16)(r >> 16);
}

__device__ __forceinline__ void glds16(const void* g, void* l) {
  __builtin_amdgcn_global_load_lds(
      (const __attribute__((address_space(1))) u32*)g,
      (__attribute__((address_space(3))) u32*)l, 16, 0, 0);
}

// ---------------- cast fp32 -> bf16, 8 elems/thread ----------------
__global__ void cast_bf16_kernel(const float* __restrict__ src, u16* __restrict__ dst, int n8) {
  int i = blockIdx.x * blockDim.x + threadIdx.x;
  if (i >= n8) return;
  const float4* s4 = (const float4*)src;
  float4 a = s4[2 * i], b = s4[2 * i + 1];
  uint4 o;
  o.x = (u32)f2bf(a.x) | ((u32)f2bf(a.y) << 16);
  o.y = (u32)f2bf(a.z) | ((u32)f2bf(a.w) << 16);
  o.z = (u32)f2bf(b.x) | ((u32)f2bf(b.y) << 16);
  o.w = (u32)f2bf(b.z) | ((u32)f2bf(b.w) << 16);
  ((uint4*)dst)[i] = o;
}

// ---------------- router: one wave per token, NO atomics ----------------
__global__ __launch_bounds__(256) void router_kernel(
    const float* __restrict__ x, const float* __restrict__ wg,
    int* __restrict__ tki, float* __restrict__ tkp,
    float* __restrict__ probs, float* __restrict__ lse2) {
  int lane = threadIdx.x & 63;
  int t = blockIdx.x * 4 + (threadIdx.x >> 6);
  const float* xr = x + (long)t * DIM;
  float acc[NE];
#pragma unroll
  for (int e = 0; e < NE; e++) acc[e] = 0.f;
  for (int i = 0; i < DIM / 64; i++) {
    float xv = xr[lane + 64 * i];
#pragma unroll
    for (int e = 0; e < NE; e++) acc[e] += xv * wg[e * DIM + lane + 64 * i];
  }
#pragma unroll
  for (int off = 32; off > 0; off >>= 1) {
#pragma unroll
    for (int e = 0; e < NE; e++) acc[e] += __shfl_xor(acc[e], off);
  }
  if (lane == 0) {
    float m = acc[0];
#pragma unroll
    for (int e = 1; e < NE; e++) m = fmaxf(m, acc[e]);
    float p[NE], s = 0.f;
#pragma unroll
    for (int e = 0; e < NE; e++) { p[e] = __expf(acc[e] - m); s += p[e]; }
    float inv = 1.f / s;
    int e0 = 0;
#pragma unroll
    for (int e = 1; e < NE; e++) if (acc[e] > acc[e0]) e0 = e;
    int e1 = (e0 == 0) ? 1 : 0;
#pragma unroll
    for (int e = 0; e < NE; e++) if (e != e0 && acc[e] > acc[e1]) e1 = e;
    float p0 = p[e0] * inv, p1 = p[e1] * inv;
    float rn = 1.f / (p0 + p1);
    tki[2 * t] = e0; tki[2 * t + 1] = e1;
    tkp[2 * t] = p0 * rn; tkp[2 * t + 1] = p1 * rn;
    float4 pa = {p[0] * inv, p[1] * inv, p[2] * inv, p[3] * inv};
    float4 pb = {p[4] * inv, p[5] * inv, p[6] * inv, p[7] * inv};
    ((float4*)(probs + t * 8))[0] = pa;
    ((float4*)(probs + t * 8))[1] = pb;
    float lse = __logf(s) + m;
    lse2[t] = lse * lse;
  }
}

// ---------------- reduce router stats: few atomics total ----------------
__global__ __launch_bounds__(1024) void reduce_router_kernel(
    const int* __restrict__ tki, const float* __restrict__ probs, const float* __restrict__ lse2,
    int* __restrict__ fcnt, float* __restrict__ psum, float* __restrict__ zsum) {
  int t = blockIdx.x * 1024 + threadIdx.x;
  float4 pa = ((const float4*)(probs + t * 8))[0];
  float4 pb = ((const float4*)(probs + t * 8))[1];
  float p[8] = {pa.x, pa.y, pa.z, pa.w, pb.x, pb.y, pb.z, pb.w};
  float z = lse2[t];
  int e0 = tki[2 * t], e1 = tki[2 * t + 1];
  int fc[8];
#pragma unroll
  for (int e = 0; e < 8; e++) fc[e] = (e0 == e ? 1 : 0) + (e1 == e ? 1 : 0);
#pragma unroll
  for (int off = 32; off > 0; off >>= 1) {
#pragma unroll
    for (int e = 0; e < 8; e++) { p[e] += __shfl_xor(p[e], off); fc[e] += __shfl_xor(fc[e], off); }
    z += __shfl_xor(z, off);
  }
  __shared__ float sp[16][9];
  __shared__ int sf[16][8];
  int wv = threadIdx.x >> 6, lane = threadIdx.x & 63;
  if (lane == 0) {
#pragma unroll
    for (int e = 0; e < 8; e++) { sp[wv][e] = p[e]; sf[wv][e] = fc[e]; }
    sp[wv][8] = z;
  }
  __syncthreads();
  if (threadIdx.x < 9) {
    float s = 0.f;
    for (int w = 0; w < 16; w++) s += sp[w][threadIdx.x];
    if (threadIdx.x < 8) atomicAdd(&psum[threadIdx.x], s);
    else atomicAdd(zsum, s);
  }
  if (threadIdx.x >= 64 && threadIdx.x < 72) {
    int e = threadIdx.x - 64;
    int s = 0;
    for (int w = 0; w < 16; w++) s += sf[w][e];
    atomicAdd(&fcnt[e], s);
  }
}

// ---------------- rank + dispatch (exact capacity semantics) ----------------
__global__ __launch_bounds__(1024) void rank_dispatch_kernel(
    const int* __restrict__ tki, const float* __restrict__ tkp,
    int* __restrict__ ltk, float* __restrict__ lw, int* __restrict__ keep,
    int* __restrict__ counts, int* __restrict__ baserow) {
  __shared__ int wave_cnt[2][16][8];
  __shared__ int base[2][8];
  __shared__ int epos[8];
  int tid = threadIdx.x, wv = tid >> 6, lane = tid & 63;
  if (tid < 16) base[tid >> 3][tid & 7] = 0;
  if (tid < 8) epos[tid] = 0;
  __syncthreads();
  u64 lmask = (lane == 63) ? 0x7FFFFFFFFFFFFFFFull : ((1ull << lane) - 1ull);
  for (int c = 0; c < T_TOK / 1024; c++) {
    int t = c * 1024 + tid;
    int e0 = tki[2 * t], e1 = tki[2 * t + 1];
    float p0 = tkp[2 * t], p1 = tkp[2 * t + 1];
    int pre0 = 0, pre1 = 0;
    for (int e = 0; e < 8; e++) {
      u64 m0 = __ballot(e0 == e);
      if (e0 == e) pre0 = __popcll(m0 & lmask);
      if (lane == 0) wave_cnt[0][wv][e] = __popcll(m0);
      u64 m1 = __ballot(e1 == e);
      if (e1 == e) pre1 = __popcll(m1 & lmask);
      if (lane == 0) wave_cnt[1][wv][e] = __popcll(m1);
    }
    __syncthreads();
    if (tid < 16) {
      int k = tid >> 3, e = tid & 7;
      int run = base[k][e];
      for (int w = 0; w < 16; w++) {
        int v = wave_cnt[k][w][e];
        wave_cnt[k][w][e] = run;
        run += v;
      }
      base[k][e] = run;
    }
    __syncthreads();
    int r0 = wave_cnt[0][wv][e0] + pre0;
    int r1 = wave_cnt[1][wv][e1] + pre1;
    int k0 = (r0 < CAP) ? 1 : 0;
    int k1 = (r1 < CAP) ? 1 : 0;
    keep[t] = k0 | (k1 << 1);
    if (k0) { int p = atomicAdd(&epos[e0], 1); ltk[e0 * LSTR + p] = (t << 1); lw[e0 * LSTR + p] = p0; }
    if (k1) { int p = atomicAdd(&epos[e1], 1); ltk[e1 * LSTR + p] = (t << 1) | 1; lw[e1 * LSTR + p] = p1; }
    __syncthreads();
  }
  if (tid == 0) {
    int run = 0;
    for (int e = 0; e < 8; e++) { counts[e] = epos[e]; baserow[e] = run; run += epos[e]; }
  }
}

// ---------------- GEMM1: H = silu(x@Wg^T) * (x@Wu^T), gathered rows ----------------
__global__ __launch_bounds__(256, 2) void gemm1_kernel(
    const u16* __restrict__ xb, const u16* __restrict__ wgb, const u16* __restrict__ wub,
    u16* __restrict__ H, const int* __restrict__ counts, const int* __restrict__ baserow,
    const int* __restrict__ ltk) {
  int e = blockIdx.x / MAXMT, mt = blockIdx.x % MAXMT;
  int cnt = counts[e];
  if (mt * 128 >= cnt) return;
  int nt = blockIdx.y;
  __shared__ u16 As[128 * 32];
  __shared__ u16 Bg[128 * 32];
  __shared__ u16 Bu[128 * 32];
  __shared__ int toks[128];
  int tid = threadIdx.x;
  if (tid < 128) {
    int r = mt * 128 + tid; if (r > cnt - 1) r = cnt - 1;
    toks[tid] = ltk[e * LSTR + r] >> 1;
  }
  __syncthreads();
  int rq = tid >> 2;
  int kc = (tid & 3) * 8;
  long tA0 = toks[rq], tA1 = toks[64 + rq];
  const u16* gA0 = xb + tA0 * DIM + kc;
  const u16* gA1 = xb + tA1 * DIM + kc;
  long bOff = ((long)e * FF + nt * 128 + rq) * DIM + kc;
  const u16* gG0 = wgb + bOff;
  const u16* gG1 = wgb + bOff + 64l * DIM;
  const u16* gU0 = wub + bOff;
  const u16* gU1 = wub + bOff + 64l * DIM;
  u16* dA0 = As + tid * 8; u16* dA1 = As + (256 + tid) * 8;
  u16* dG0 = Bg + tid * 8; u16* dG1 = Bg + (256 + tid) * 8;
  u16* dU0 = Bu + tid * 8; u16* dU1 = Bu + (256 + tid) * 8;

  int lane = tid & 63, wv = tid >> 6;
  int wm = (wv & 1) * 64, wn = (wv >> 1) * 64;
  int lrow = lane & 15, quad = lane >> 4;

  f4v zero = {0.f, 0.f, 0.f, 0.f};
  f4v accg[4][4], accu[4][4];
#pragma unroll
  for (int i = 0; i < 4; i++)
#pragma unroll
    for (int j = 0; j < 4; j++) { accg[i][j] = zero; accu[i][j] = zero; }

  for (int kt = 0; kt < DIM / 32; kt++) {
    int ko = kt * 32;
    __syncthreads();
    glds16(gA0 + ko, dA0); glds16(gA1 + ko, dA1);
    glds16(gG0 + ko, dG0); glds16(gG1 + ko, dG1);
    glds16(gU0 + ko, dU0); glds16(gU1 + ko, dU1);
    __syncthreads();
    s8v a[4], bg[4], bu[4];
#pragma unroll
    for (int i = 0; i < 4; i++)
      a[i] = *(const s8v*)&As[(wm + i * 16 + lrow) * 32 + quad * 8];
#pragma unroll
    for (int j = 0; j < 4; j++) {
      bg[j] = *(const s8v*)&Bg[(wn + j * 16 + lrow) * 32 + quad * 8];
      bu[j] = *(const s8v*)&Bu[(wn + j * 16 + lrow) * 32 + quad * 8];
    }
#pragma unroll
    for (int i = 0; i < 4; i++)
#pragma unroll
      for (int j = 0; j < 4; j++) {
        accg[i][j] = __builtin_amdgcn_mfma_f32_16x16x32_bf16(a[i], bg[j], accg[i][j], 0, 0, 0);
        accu[i][j] = __builtin_amdgcn_mfma_f32_16x16x32_bf16(a[i], bu[j], accu[i][j], 0, 0, 0);
      }
  }
  long hb = (long)baserow[e] + (long)mt * 128;
#pragma unroll
  for (int i = 0; i < 4; i++) {
#pragma unroll
    for (int r = 0; r < 4; r++) {
      int m = wm + i * 16 + quad * 4 + r;
      if (mt * 128 + m < cnt) {
#pragma unroll
        for (int j = 0; j < 4; j++) {
          float g = accg[i][j][r], u = accu[i][j][r];
          float h = g / (1.f + __expf(-g)) * u;
          H[(hb + m) * FF + nt * 128 + wn + j * 16 + lrow] = f2bf(h);
        }
      }
    }
  }
}

// ---------------- GEMM2: y = H @ wo^T, scaled by combine weight ----------------
__global__ __launch_bounds__(256, 2) void gemm2_kernel(
    const u16* __restrict__ H, const u16* __restrict__ wob,
    float* __restrict__ ybuf, const int* __restrict__ counts, const int* __restrict__ baserow,
    const int* __restrict__ ltk, const float* __restrict__ lw) {
  int e = blockIdx.x / MAXMT, mt = blockIdx.x % MAXMT;
  int cnt = counts[e];
  if (mt * 128 >= cnt) return;
  int nt = blockIdx.y;
  __shared__ u16 As[128 * 32];
  __shared__ u16 Bs[128 * 32];
  __shared__ int stok[128];
  __shared__ float sw[128];
  int tid = threadIdx.x;
  if (tid < 128) {
    int r = mt * 128 + tid; if (r > cnt - 1) r = cnt - 1;
    stok[tid] = ltk[e * LSTR + r];
    sw[tid] = lw[e * LSTR + r];
  }
  long hb = (long)baserow[e] + (long)mt * 128;
  int rq = tid >> 2, kc = (tid & 3) * 8;
  const u16* gA0 = H + (hb + rq) * FF + kc;
  const u16* gA1 = gA0 + 64l * FF;
  long bOff = ((long)e * DIM + nt * 128 + rq) * FF + kc;
  const u16* gB0 = wob + bOff;
  const u16* gB1 = gB0 + 64l * FF;
  u16* dA0 = As + tid * 8; u16* dA1 = As + (256 + tid) * 8;
  u16* dB0 = Bs + tid * 8; u16* dB1 = Bs + (256 + tid) * 8;
  int lane = tid & 63, wv = tid >> 6;
  int wm = (wv & 1) * 64, wn = (wv >> 1) * 64;
  int lrow = lane & 15, quad = lane >> 4;
  f4v zero = {0.f, 0.f, 0.f, 0.f};
  f4v acc[4][4];
#pragma unroll
  for (int i = 0; i < 4; i++)
#pragma unroll
    for (int j = 0; j < 4; j++) acc[i][j] = zero;

  for (int kt = 0; kt < FF / 32; kt++) {
    int ko = kt * 32;
    __syncthreads();
    glds16(gA0 + ko, dA0); glds16(gA1 + ko, dA1);
    glds16(gB0 + ko, dB0); glds16(gB1 + ko, dB1);
    __syncthreads();
    s8v a[4], b[4];
#pragma unroll
    for (int i = 0; i < 4; i++)
      a[i] = *(const s8v*)&As[(wm + i * 16 + lrow) * 32 + quad * 8];
#pragma unroll
    for (int j = 0; j < 4; j++)
      b[j] = *(const s8v*)&Bs[(wn + j * 16 + lrow) * 32 + quad * 8];
#pragma unroll
    for (int i = 0; i < 4; i++)
#pragma unroll
      for (int j = 0; j < 4; j++)
        acc[i][j] = __builtin_amdgcn_mfma_f32_16x16x32_bf16(a[i], b[j], acc[i][j], 0, 0, 0);
  }
#pragma unroll
  for (int i = 0; i < 4; i++) {
#pragma unroll
    for (int r = 0; r < 4; r++) {
      int m = wm + i * 16 + quad * 4 + r;
      if (mt * 128 + m < cnt) {
        int entry = stok[m];
        int t = entry >> 1, k = entry & 1;
        float w = sw[m];
        long ob = ((long)(k * T_TOK + t)) * DIM + nt * 128;
#pragma unroll
        for (int j = 0; j < 4; j++)
          ybuf[ob + wn + j * 16 + lrow] = acc[i][j][r] * w;
      }
    }
  }
}

// ---------------- combine two slots -> out ----------------
__global__ void combine_kernel(const float* __restrict__ ybuf, const int* __restrict__ keep,
                               float* __restrict__ out) {
  int idx = blockIdx.x * 256 + threadIdx.x;
  int t = idx / (DIM / 4);
  int km = keep[t];
  const float4* y4 = (const float4*)ybuf;
  float4 r = {0.f, 0.f, 0.f, 0.f};
  if (km & 1) r = y4[idx];
  if (km & 2) {
    float4 b = y4[T_TOK * (DIM / 4) + idx];
    r.x += b.x; r.y += b.y; r.z += b.z; r.w += b.w;
  }
  ((float4*)out)[idx] = r;
}

// ---------------- aux loss ----------------
__global__ void aux_kernel(const int* __restrict__ fcnt, const float* __restrict__ psum,
                           const float* __restrict__ zsum, float* __restrict__ outaux) {
  if (threadIdx.x == 0 && blockIdx.x == 0) {
    float lb = 0.f;
    for (int e = 0; e < 8; e++)
      lb += ((float)fcnt[e] / (float)(T_TOK * 2)) * (psum[e] / (float)T_TOK);
    lb *= 8.f;
    float z = zsum[0] / (float)T_TOK;
    outaux[0] = 0.01f * lb + 0.001f * z;
  }
}

extern "C" void kernel_launch(void* const* d_in, const int* in_sizes, int n_in,
                              void* d_out, int out_size, void* d_ws, size_t ws_size,
                              hipStream_t stream) {
  const float* x = (const float*)d_in[0];
  const float* wgate = (const float*)d_in[1];
  const float* wig = (const float*)d_in[2];
  const float* wiu = (const float*)d_in[3];
  const float* wo = (const float*)d_in[4];
  float* out = (float*)d_out;

  char* ws = (char*)d_ws;
  size_t off = 0;
  auto alloc = [&](size_t bytes) {
    void* p = ws + off;
    off += (bytes + 255) & ~(size_t)255;
    return p;
  };
  int* ctrl = (int*)alloc(256);
  u16* xb = (u16*)alloc((size_t)T_TOK * DIM * 2);
  u16* wgb = (u16*)alloc((size_t)NE * FF * DIM * 2);
  u16* wub = (u16*)alloc((size_t)NE * FF * DIM * 2);
  u16* wob = (u16*)alloc((size_t)NE * DIM * FF * 2);
  u16* Hbuf = (u16*)alloc((size_t)(T_TOK * 2 + 128) * FF * 2);
  float* ybuf = (float*)alloc((size_t)2 * T_TOK * DIM * 4);
  int* tki = (int*)alloc((size_t)T_TOK * 2 * 4);
  float* tkp = (float*)alloc((size_t)T_TOK * 2 * 4);
  int* ltk = (int*)alloc((size_t)NE * LSTR * 4);
  float* lw = (float*)alloc((size_t)NE * LSTR * 4);
  int* keep = (int*)alloc((size_t)T_TOK * 4);
  float* probs = (float*)alloc((size_t)T_TOK * 8 * 4);
  float* lse2 = (float*)alloc((size_t)T_TOK * 4);

  int* fcnt = ctrl;
  int* counts = ctrl + 8;
  int* baserow = ctrl + 16;
  float* psum = (float*)(ctrl + 24);
  float* zsum = (float*)(ctrl + 32);

  hipMemsetAsync(ctrl, 0, 256, stream);
  cast_bf16_kernel<<<T_TOK * DIM / 8 / 256, 256, 0, stream>>>(x, xb, T_TOK * DIM / 8);
  cast_bf16_kernel<<<NE * FF * DIM / 8 / 256, 256, 0, stream>>>(wig, wgb, NE * FF * DIM / 8);
  cast_bf16_kernel<<<NE * FF * DIM / 8 / 256, 256, 0, stream>>>(wiu, wub, NE * FF * DIM / 8);
  cast_bf16_kernel<<<NE * DIM * FF / 8 / 256, 256, 0, stream>>>(wo, wob, NE * DIM * FF / 8);
  router_kernel<<<T_TOK / 4, 256, 0, stream>>>(x, wgate, tki, tkp, probs, lse2);
  reduce_router_kernel<<<T_TOK / 1024, 1024, 0, stream>>>(tki, probs, lse2, fcnt, psum, zsum);
  rank_dispatch_kernel<<<1, 1024, 0, stream>>>(tki, tkp, ltk, lw, keep, counts, baserow);
  gemm1_kernel<<<dim3(NE * MAXMT, FF / 128), 256, 0, stream>>>(xb, wgb, wub, Hbuf, counts, baserow, ltk);
  gemm2_kernel<<<dim3(NE * MAXMT, DIM / 128), 256, 0, stream>>>(Hbuf, wob, ybuf, counts, baserow, ltk, lw);
  combine_kernel<<<T_TOK * DIM / 4 / 256, 256, 0, stream>>>(ybuf, keep, out);
  aux_kernel<<<1, 64, 0, stream>>>(fcnt, psum, zsum, out + (size_t)T_TOK * DIM);
}

// Round 3
// 641.722 us; speedup vs baseline: 2.4917x; 1.1717x over previous
//
#include <hip/hip_runtime.h>

typedef unsigned short u16;
typedef unsigned int u32;
typedef unsigned long long u64;

#define T_TOK 8192
#define DIM 768
#define FF 3072
#define NE 8
#define CAP 2560
#define LSTR 5120
#define MAXMT 20

typedef __attribute__((ext_vector_type(8))) short s8v;
typedef __attribute__((ext_vector_type(4))) float f4v;

__device__ __forceinline__ u16 f2bf(float f) {
  union { float f; u32 u; } v; v.f = f;
  u32 r = v.u + 0x7FFFu + ((v.u >> 16) & 1u);
  return (u16)(r >> 16);
}

__device__ __forceinline__ void glds16(const void* g, void* l) {
  __builtin_amdgcn_global_load_lds(
      (const __attribute__((address_space(1))) u32*)g,
      (__attribute__((address_space(3))) u32*)l, 16, 0, 0);
}

// ---------------- cast fp32 -> bf16, 8 elems/thread ----------------
__global__ void cast_bf16_kernel(const float* __restrict__ src, u16* __restrict__ dst, int n8) {
  int i = blockIdx.x * blockDim.x + threadIdx.x;
  if (i >= n8) return;
  const float4* s4 = (const float4*)src;
  float4 a = s4[2 * i], b = s4[2 * i + 1];
  uint4 o;
  o.x = (u32)f2bf(a.x) | ((u32)f2bf(a.y) << 16);
  o.y = (u32)f2bf(a.z) | ((u32)f2bf(a.w) << 16);
  o.z = (u32)f2bf(b.x) | ((u32)f2bf(b.y) << 16);
  o.w = (u32)f2bf(b.z) | ((u32)f2bf(b.w) << 16);
  ((uint4*)dst)[i] = o;
}

// ---------------- router: one wave per token, NO atomics ----------------
__global__ __launch_bounds__(256) void router_kernel(
    const float* __restrict__ x, const float* __restrict__ wg,
    int* __restrict__ tki, float* __restrict__ tkp,
    float* __restrict__ probs, float* __restrict__ lse2) {
  int lane = threadIdx.x & 63;
  int t = blockIdx.x * 4 + (threadIdx.x >> 6);
  const float* xr = x + (long)t * DIM;
  float acc[NE];
#pragma unroll
  for (int e = 0; e < NE; e++) acc[e] = 0.f;
  for (int i = 0; i < DIM / 64; i++) {
    float xv = xr[lane + 64 * i];
#pragma unroll
    for (int e = 0; e < NE; e++) acc[e] += xv * wg[e * DIM + lane + 64 * i];
  }
#pragma unroll
  for (int off = 32; off > 0; off >>= 1) {
#pragma unroll
    for (int e = 0; e < NE; e++) acc[e] += __shfl_xor(acc[e], off);
  }
  if (lane == 0) {
    float m = acc[0];
#pragma unroll
    for (int e = 1; e < NE; e++) m = fmaxf(m, acc[e]);
    float p[NE], s = 0.f;
#pragma unroll
    for (int e = 0; e < NE; e++) { p[e] = __expf(acc[e] - m); s += p[e]; }
    float inv = 1.f / s;
    int e0 = 0;
#pragma unroll
    for (int e = 1; e < NE; e++) if (acc[e] > acc[e0]) e0 = e;
    int e1 = (e0 == 0) ? 1 : 0;
#pragma unroll
    for (int e = 0; e < NE; e++) if (e != e0 && acc[e] > acc[e1]) e1 = e;
    float p0 = p[e0] * inv, p1 = p[e1] * inv;
    float rn = 1.f / (p0 + p1);
    tki[2 * t] = e0; tki[2 * t + 1] = e1;
    tkp[2 * t] = p0 * rn; tkp[2 * t + 1] = p1 * rn;
    float4 pa = {p[0] * inv, p[1] * inv, p[2] * inv, p[3] * inv};
    float4 pb = {p[4] * inv, p[5] * inv, p[6] * inv, p[7] * inv};
    ((float4*)(probs + t * 8))[0] = pa;
    ((float4*)(probs + t * 8))[1] = pb;
    float lse = __logf(s) + m;
    lse2[t] = lse * lse;
  }
}

// ---------------- reduce router stats: few atomics total ----------------
__global__ __launch_bounds__(1024) void reduce_router_kernel(
    const int* __restrict__ tki, const float* __restrict__ probs, const float* __restrict__ lse2,
    int* __restrict__ fcnt, float* __restrict__ psum, float* __restrict__ zsum) {
  int t = blockIdx.x * 1024 + threadIdx.x;
  float4 pa = ((const float4*)(probs + t * 8))[0];
  float4 pb = ((const float4*)(probs + t * 8))[1];
  float p[8] = {pa.x, pa.y, pa.z, pa.w, pb.x, pb.y, pb.z, pb.w};
  float z = lse2[t];
  int e0 = tki[2 * t], e1 = tki[2 * t + 1];
  int fc[8];
#pragma unroll
  for (int e = 0; e < 8; e++) fc[e] = (e0 == e ? 1 : 0) + (e1 == e ? 1 : 0);
#pragma unroll
  for (int off = 32; off > 0; off >>= 1) {
#pragma unroll
    for (int e = 0; e < 8; e++) { p[e] += __shfl_xor(p[e], off); fc[e] += __shfl_xor(fc[e], off); }
    z += __shfl_xor(z, off);
  }
  __shared__ float sp[16][9];
  __shared__ int sf[16][8];
  int wv = threadIdx.x >> 6, lane = threadIdx.x & 63;
  if (lane == 0) {
#pragma unroll
    for (int e = 0; e < 8; e++) { sp[wv][e] = p[e]; sf[wv][e] = fc[e]; }
    sp[wv][8] = z;
  }
  __syncthreads();
  if (threadIdx.x < 9) {
    float s = 0.f;
    for (int w = 0; w < 16; w++) s += sp[w][threadIdx.x];
    if (threadIdx.x < 8) atomicAdd(&psum[threadIdx.x], s);
    else atomicAdd(zsum, s);
  }
  if (threadIdx.x >= 64 && threadIdx.x < 72) {
    int e = threadIdx.x - 64;
    int s = 0;
    for (int w = 0; w < 16; w++) s += sf[w][e];
    atomicAdd(&fcnt[e], s);
  }
}

// ---------------- rank + dispatch (exact capacity semantics) ----------------
__global__ __launch_bounds__(1024) void rank_dispatch_kernel(
    const int* __restrict__ tki, const float* __restrict__ tkp,
    int* __restrict__ ltk, float* __restrict__ lw,
    int* __restrict__ counts, int* __restrict__ baserow) {
  __shared__ int wave_cnt[2][16][8];
  __shared__ int base[2][8];
  __shared__ int epos[8];
  int tid = threadIdx.x, wv = tid >> 6, lane = tid & 63;
  if (tid < 16) base[tid >> 3][tid & 7] = 0;
  if (tid < 8) epos[tid] = 0;
  __syncthreads();
  u64 lmask = (lane == 63) ? 0x7FFFFFFFFFFFFFFFull : ((1ull << lane) - 1ull);
  for (int c = 0; c < T_TOK / 1024; c++) {
    int t = c * 1024 + tid;
    int e0 = tki[2 * t], e1 = tki[2 * t + 1];
    float p0 = tkp[2 * t], p1 = tkp[2 * t + 1];
    int pre0 = 0, pre1 = 0;
    for (int e = 0; e < 8; e++) {
      u64 m0 = __ballot(e0 == e);
      if (e0 == e) pre0 = __popcll(m0 & lmask);
      if (lane == 0) wave_cnt[0][wv][e] = __popcll(m0);
      u64 m1 = __ballot(e1 == e);
      if (e1 == e) pre1 = __popcll(m1 & lmask);
      if (lane == 0) wave_cnt[1][wv][e] = __popcll(m1);
    }
    __syncthreads();
    if (tid < 16) {
      int k = tid >> 3, e = tid & 7;
      int run = base[k][e];
      for (int w = 0; w < 16; w++) {
        int v = wave_cnt[k][w][e];
        wave_cnt[k][w][e] = run;
        run += v;
      }
      base[k][e] = run;
    }
    __syncthreads();
    int r0 = wave_cnt[0][wv][e0] + pre0;
    int r1 = wave_cnt[1][wv][e1] + pre1;
    if (r0 < CAP) { int p = atomicAdd(&epos[e0], 1); ltk[e0 * LSTR + p] = (t << 1); lw[e0 * LSTR + p] = p0; }
    if (r1 < CAP) { int p = atomicAdd(&epos[e1], 1); ltk[e1 * LSTR + p] = (t << 1) | 1; lw[e1 * LSTR + p] = p1; }
    __syncthreads();
  }
  if (tid == 0) {
    int run = 0;
    for (int e = 0; e < 8; e++) { counts[e] = epos[e]; baserow[e] = run; run += epos[e]; }
  }
}

// ---------------- GEMM1: H = silu(x@Wg^T) * (x@Wu^T), tile 128x64, XCD swizzle ----------------
__global__ __launch_bounds__(256, 2) void gemm1_kernel(
    const u16* __restrict__ xb, const u16* __restrict__ wgb, const u16* __restrict__ wub,
    u16* __restrict__ H, const int* __restrict__ counts, const int* __restrict__ baserow,
    const int* __restrict__ ltk) {
  // swizzle: groups g=(e*48+nt) share weights; members mt on same XCD
  int id = blockIdx.x;
  int xcd = id & 7;
  int q = id >> 3;          // [0, 960)
  int gg = q / MAXMT;       // [0, 48)
  int mt = q - gg * MAXMT;  // [0, 20)
  int g = gg * 8 + xcd;     // [0, 384)
  int e = g / 48;
  int nt = g - e * 48;      // [0, 48)
  int cnt = counts[e];
  if (mt * 128 >= cnt) return;

  __shared__ u16 As[128 * 32];
  __shared__ u16 Bg[64 * 32];
  __shared__ u16 Bu[64 * 32];
  __shared__ int toks[128];
  int tid = threadIdx.x;
  if (tid < 128) {
    int r = mt * 128 + tid; if (r > cnt - 1) r = cnt - 1;
    toks[tid] = ltk[e * LSTR + r] >> 1;
  }
  __syncthreads();
  int rq = tid >> 2;
  int kc = (tid & 3) * 8;
  long tA0 = toks[rq], tA1 = toks[64 + rq];
  const u16* gA0 = xb + tA0 * DIM + kc;
  const u16* gA1 = xb + tA1 * DIM + kc;
  long bOff = ((long)e * FF + nt * 64 + rq) * DIM + kc;
  const u16* gG0 = wgb + bOff;
  const u16* gU0 = wub + bOff;
  u16* dA0 = As + tid * 8; u16* dA1 = As + (256 + tid) * 8;
  u16* dG0 = Bg + tid * 8;
  u16* dU0 = Bu + tid * 8;

  int lane = tid & 63, wv = tid >> 6;
  int wm = (wv & 1) * 64, wn = (wv >> 1) * 32;
  int lrow = lane & 15, quad = lane >> 4;

  f4v zero = {0.f, 0.f, 0.f, 0.f};
  f4v accg[4][2], accu[4][2];
#pragma unroll
  for (int i = 0; i < 4; i++)
#pragma unroll
    for (int j = 0; j < 2; j++) { accg[i][j] = zero; accu[i][j] = zero; }

  for (int kt = 0; kt < DIM / 32; kt++) {
    int ko = kt * 32;
    __syncthreads();
    glds16(gA0 + ko, dA0); glds16(gA1 + ko, dA1);
    glds16(gG0 + ko, dG0);
    glds16(gU0 + ko, dU0);
    __syncthreads();
    s8v a[4], bg[2], bu[2];
#pragma unroll
    for (int i = 0; i < 4; i++)
      a[i] = *(const s8v*)&As[(wm + i * 16 + lrow) * 32 + quad * 8];
#pragma unroll
    for (int j = 0; j < 2; j++) {
      bg[j] = *(const s8v*)&Bg[(wn + j * 16 + lrow) * 32 + quad * 8];
      bu[j] = *(const s8v*)&Bu[(wn + j * 16 + lrow) * 32 + quad * 8];
    }
#pragma unroll
    for (int i = 0; i < 4; i++)
#pragma unroll
      for (int j = 0; j < 2; j++) {
        accg[i][j] = __builtin_amdgcn_mfma_f32_16x16x32_bf16(a[i], bg[j], accg[i][j], 0, 0, 0);
        accu[i][j] = __builtin_amdgcn_mfma_f32_16x16x32_bf16(a[i], bu[j], accu[i][j], 0, 0, 0);
      }
  }
  long hb = (long)baserow[e] + (long)mt * 128;
#pragma unroll
  for (int i = 0; i < 4; i++) {
#pragma unroll
    for (int r = 0; r < 4; r++) {
      int m = wm + i * 16 + quad * 4 + r;
      if (mt * 128 + m < cnt) {
#pragma unroll
        for (int j = 0; j < 2; j++) {
          float gv = accg[i][j][r], uv = accu[i][j][r];
          float h = gv / (1.f + __expf(-gv)) * uv;
          H[(hb + m) * FF + nt * 64 + wn + j * 16 + lrow] = f2bf(h);
        }
      }
    }
  }
}

// ---------------- GEMM2: out += (H @ wo^T) * w, atomic scatter, XCD swizzle ----------------
__global__ __launch_bounds__(256, 2) void gemm2_kernel(
    const u16* __restrict__ H, const u16* __restrict__ wob,
    float* __restrict__ out, const int* __restrict__ counts, const int* __restrict__ baserow,
    const int* __restrict__ ltk, const float* __restrict__ lw) {
  // swizzle: groups g=(e*20+mt) share H rows; members nt on same XCD
  int id = blockIdx.x;
  int xcd = id & 7;
  int q = id >> 3;        // [0, 120)
  int gg = q / 6;         // [0, 20)
  int nt = q - gg * 6;    // [0, 6)
  int g = gg * 8 + xcd;   // [0, 160)
  int e = g / MAXMT;
  int mt = g - e * MAXMT;
  int cnt = counts[e];
  if (mt * 128 >= cnt) return;

  __shared__ u16 As[128 * 32];
  __shared__ u16 Bs[128 * 32];
  __shared__ int stok[128];
  __shared__ float sw[128];
  int tid = threadIdx.x;
  if (tid < 128) {
    int r = mt * 128 + tid; if (r > cnt - 1) r = cnt - 1;
    stok[tid] = ltk[e * LSTR + r];
    sw[tid] = lw[e * LSTR + r];
  }
  long hb = (long)baserow[e] + (long)mt * 128;
  int rq = tid >> 2, kc = (tid & 3) * 8;
  const u16* gA0 = H + (hb + rq) * FF + kc;
  const u16* gA1 = gA0 + 64l * FF;
  long bOff = ((long)e * DIM + nt * 128 + rq) * FF + kc;
  const u16* gB0 = wob + bOff;
  const u16* gB1 = gB0 + 64l * FF;
  u16* dA0 = As + tid * 8; u16* dA1 = As + (256 + tid) * 8;
  u16* dB0 = Bs + tid * 8; u16* dB1 = Bs + (256 + tid) * 8;
  int lane = tid & 63, wv = tid >> 6;
  int wm = (wv & 1) * 64, wn = (wv >> 1) * 64;
  int lrow = lane & 15, quad = lane >> 4;
  f4v zero = {0.f, 0.f, 0.f, 0.f};
  f4v acc[4][4];
#pragma unroll
  for (int i = 0; i < 4; i++)
#pragma unroll
    for (int j = 0; j < 4; j++) acc[i][j] = zero;

  for (int kt = 0; kt < FF / 32; kt++) {
    int ko = kt * 32;
    __syncthreads();
    glds16(gA0 + ko, dA0); glds16(gA1 + ko, dA1);
    glds16(gB0 + ko, dB0); glds16(gB1 + ko, dB1);
    __syncthreads();
    s8v a[4], b[4];
#pragma unroll
    for (int i = 0; i < 4; i++)
      a[i] = *(const s8v*)&As[(wm + i * 16 + lrow) * 32 + quad * 8];
#pragma unroll
    for (int j = 0; j < 4; j++)
      b[j] = *(const s8v*)&Bs[(wn + j * 16 + lrow) * 32 + quad * 8];
#pragma unroll
    for (int i = 0; i < 4; i++)
#pragma unroll
      for (int j = 0; j < 4; j++)
        acc[i][j] = __builtin_amdgcn_mfma_f32_16x16x32_bf16(a[i], b[j], acc[i][j], 0, 0, 0);
  }
#pragma unroll
  for (int i = 0; i < 4; i++) {
#pragma unroll
    for (int r = 0; r < 4; r++) {
      int m = wm + i * 16 + quad * 4 + r;
      if (mt * 128 + m < cnt) {
        int entry = stok[m];
        int t = entry >> 1;
        float w = sw[m];
        long ob = (long)t * DIM + nt * 128;
#pragma unroll
        for (int j = 0; j < 4; j++)
          atomicAdd(&out[ob + wn + j * 16 + lrow], acc[i][j][r] * w);
      }
    }
  }
}

// ---------------- aux loss ----------------
__global__ void aux_kernel(const int* __restrict__ fcnt, const float* __restrict__ psum,
                           const float* __restrict__ zsum, float* __restrict__ outaux) {
  if (threadIdx.x == 0 && blockIdx.x == 0) {
    float lb = 0.f;
    for (int e = 0; e < 8; e++)
      lb += ((float)fcnt[e] / (float)(T_TOK * 2)) * (psum[e] / (float)T_TOK);
    lb *= 8.f;
    float z = zsum[0] / (float)T_TOK;
    outaux[0] = 0.01f * lb + 0.001f * z;
  }
}

extern "C" void kernel_launch(void* const* d_in, const int* in_sizes, int n_in,
                              void* d_out, int out_size, void* d_ws, size_t ws_size,
                              hipStream_t stream) {
  const float* x = (const float*)d_in[0];
  const float* wgate = (const float*)d_in[1];
  const float* wig = (const float*)d_in[2];
  const float* wiu = (const float*)d_in[3];
  const float* wo = (const float*)d_in[4];
  float* out = (float*)d_out;

  char* ws = (char*)d_ws;
  size_t off = 0;
  auto alloc = [&](size_t bytes) {
    void* p = ws + off;
    off += (bytes + 255) & ~(size_t)255;
    return p;
  };
  int* ctrl = (int*)alloc(256);
  u16* xb = (u16*)alloc((size_t)T_TOK * DIM * 2);
  u16* wgb = (u16*)alloc((size_t)NE * FF * DIM * 2);
  u16* wub = (u16*)alloc((size_t)NE * FF * DIM * 2);
  u16* wob = (u16*)alloc((size_t)NE * DIM * FF * 2);
  u16* Hbuf = (u16*)alloc((size_t)(T_TOK * 2 + 128) * FF * 2);
  int* tki = (int*)alloc((size_t)T_TOK * 2 * 4);
  float* tkp = (float*)alloc((size_t)T_TOK * 2 * 4);
  int* ltk = (int*)alloc((size_t)NE * LSTR * 4);
  float* lw = (float*)alloc((size_t)NE * LSTR * 4);
  float* probs = (float*)alloc((size_t)T_TOK * 8 * 4);
  float* lse2 = (float*)alloc((size_t)T_TOK * 4);

  int* fcnt = ctrl;
  int* counts = ctrl + 8;
  int* baserow = ctrl + 16;
  float* psum = (float*)(ctrl + 24);
  float* zsum = (float*)(ctrl + 32);

  hipMemsetAsync(ctrl, 0, 256, stream);
  hipMemsetAsync(out, 0, (size_t)out_size * 4, stream);
  cast_bf16_kernel<<<T_TOK * DIM / 8 / 256, 256, 0, stream>>>(x, xb, T_TOK * DIM / 8);
  cast_bf16_kernel<<<NE * FF * DIM / 8 / 256, 256, 0, stream>>>(wig, wgb, NE * FF * DIM / 8);
  cast_bf16_kernel<<<NE * FF * DIM / 8 / 256, 256, 0, stream>>>(wiu, wub, NE * FF * DIM / 8);
  cast_bf16_kernel<<<NE * DIM * FF / 8 / 256, 256, 0, stream>>>(wo, wob, NE * DIM * FF / 8);
  router_kernel<<<T_TOK / 4, 256, 0, stream>>>(x, wgate, tki, tkp, probs, lse2);
  reduce_router_kernel<<<T_TOK / 1024, 1024, 0, stream>>>(tki, probs, lse2, fcnt, psum, zsum);
  rank_dispatch_kernel<<<1, 1024, 0, stream>>>(tki, tkp, ltk, lw, counts, baserow);
  gemm1_kernel<<<8 * 48 * MAXMT, 256, 0, stream>>>(xb, wgb, wub, Hbuf, counts, baserow, ltk);
  gemm2_kernel<<<8 * MAXMT * 6, 256, 0, stream>>>(Hbuf, wob, out, counts, baserow, ltk, lw);
  aux_kernel<<<1, 64, 0, stream>>>(fcnt, psum, zsum, out + (size_t)T_TOK * DIM);
}